// Round 5
// baseline (984.839 us; speedup 1.0000x reference)
//
#include <hip/hip_runtime.h>
#include <hip/hip_bf16.h>

#define DFEAT 64
#define EPSBN 1e-5f
#define SCB 2048   // elements per scan block (256 threads x 8)

// ---------------- degree histogram (int atomics) ----------------
__global__ void hist_kernel(const int* __restrict__ src, const int* __restrict__ dst,
                            int* __restrict__ deg_out, int* __restrict__ deg_in, int E) {
    int e = blockIdx.x * blockDim.x + threadIdx.x;
    if (e < E) {
        atomicAdd(&deg_out[src[e]], 1);
        atomicAdd(&deg_in[dst[e]], 1);
    }
}

// ---------------- scan pass 1: per-block sums of deg_in ----------------
__global__ void scan1_kernel(const int* __restrict__ deg, int* __restrict__ bsum, int N) {
    __shared__ int red[256];
    int t = threadIdx.x;
    int base = blockIdx.x * SCB + t * 8;
    int s = 0;
    #pragma unroll
    for (int j = 0; j < 8; ++j) { int idx = base + j; if (idx < N) s += deg[idx]; }
    red[t] = s;
    __syncthreads();
    for (int d = 128; d > 0; d >>= 1) { if (t < d) red[t] += red[t + d]; __syncthreads(); }
    if (t == 0) bsum[blockIdx.x] = red[0];
}

// ---------------- scan pass 2: one-wave shuffle exclusive scan (NB <= 64) ----------------
__global__ void scan2_kernel(int* __restrict__ bsum, int* __restrict__ row_start, int NB, int N) {
    int lane = threadIdx.x & 63;
    int v = (lane < NB) ? bsum[lane] : 0;
    int incl = v;
    #pragma unroll
    for (int off = 1; off < 64; off <<= 1) {
        int t = __shfl_up(incl, off);
        if (lane >= off) incl += t;
    }
    if (lane < NB) bsum[lane] = incl - v;
    if (lane == 63) row_start[N] = incl;   // total == E
}

// ---------------- scan pass 3: full exclusive scan -> row_start ----------------
__global__ void scan3_kernel(const int* __restrict__ deg, const int* __restrict__ bsum,
                             int* __restrict__ row_start, int N) {
    __shared__ int sc[256];
    int t = threadIdx.x;
    int base = blockIdx.x * SCB + t * 8;
    int v[8], ex[8];
    int s = 0;
    #pragma unroll
    for (int j = 0; j < 8; ++j) {
        int idx = base + j;
        v[j] = (idx < N) ? deg[idx] : 0;
        ex[j] = s;
        s += v[j];
    }
    sc[t] = s;
    __syncthreads();
    for (int d = 1; d < 256; d <<= 1) {
        int vv = (t >= d) ? sc[t - d] : 0;
        __syncthreads();
        sc[t] += vv;
        __syncthreads();
    }
    int toff = sc[t] - s + bsum[blockIdx.x];
    #pragma unroll
    for (int j = 0; j < 8; ++j) {
        int idx = base + j;
        if (idx < N) row_start[idx] = toff + ex[j];
    }
}

// ---------------- counting-sort edges by dst, pack (src, coef) ----------------
__global__ void fill_kernel(const int* __restrict__ src, const int* __restrict__ dst,
                            const int* __restrict__ deg_out, const int* __restrict__ row_start,
                            int* __restrict__ cursor, int2* __restrict__ epack, int E) {
    int e = blockIdx.x * blockDim.x + threadIdx.x;
    if (e < E) {
        int d = dst[e], s = src[e];
        int pos = atomicAdd(&cursor[d], 1);
        float coef = rsqrtf((float)max(deg_out[s], 1));
        epack[row_start[d] + pos] = make_int2(s, __float_as_int(coef));
    }
}

// ---------------- SpMM: ONE dst row per wave, massive TLP, no atomics ----------------
// wave loads its row's edge descriptors with one coalesced load (epack[beg+lane]),
// shfl-broadcasts feed batches of 8 independent x-row loads, plain store to agg.
__global__ __launch_bounds__(256, 6) void spmm_kernel(
        const float* __restrict__ x, const int* __restrict__ row_start,
        const int2* __restrict__ epack, float* __restrict__ agg, int N) {
    int lane = threadIdx.x & 63;
    int r = blockIdx.x * 4 + (threadIdx.x >> 6);
    if (r >= N) return;
    int beg = row_start[r];
    int end = row_start[r + 1];
    float acc = 0.f;
    for (int cb = beg; cb < end; cb += 64) {
        int take = min(64, end - cb);
        int2 p = (lane < take) ? epack[cb + lane] : make_int2(0, 0);
        int j = 0;
        for (; j + 8 <= take; j += 8) {
            int sj[8]; float cj[8], v[8];
            #pragma unroll
            for (int u = 0; u < 8; ++u) {
                sj[u] = __shfl(p.x, j + u);
                cj[u] = __int_as_float(__shfl(p.y, j + u));
            }
            #pragma unroll
            for (int u = 0; u < 8; ++u) v[u] = x[(size_t)sj[u] * DFEAT + lane];
            #pragma unroll
            for (int u = 0; u < 8; ++u) acc = fmaf(v[u], cj[u], acc);
        }
        for (; j < take; ++j) {
            int s = __shfl(p.x, j);
            float c = __int_as_float(__shfl(p.y, j));
            acc = fmaf(x[(size_t)s * DFEAT + lane], c, acc);
        }
    }
    acc *= rsqrtf((float)max(end - beg, 1));   // norm_dst
    agg[(size_t)r * DFEAT + lane] = acc;       // exclusive row: plain coalesced store
}

// ---------------- GEMM (in place on y==agg) + BN stats ----------------
// one block = one 64-row tile; reads tile to LDS (float4), then register GEMM:
// lane=row, wave wu -> 16 cols. Disjoint tiles -> in-place safe.
__global__ __launch_bounds__(256) void gemm_bn_kernel(
        const float* __restrict__ W, const float* __restrict__ bvec,
        float* __restrict__ y, float* __restrict__ sums, float* __restrict__ sumsq,
        int N) {
    __shared__ float Wlds[DFEAT * DFEAT];
    __shared__ float A[64][65];
    int tid = threadIdx.x;
    int r0 = blockIdx.x * 64;

    for (int i = tid; i < DFEAT * DFEAT; i += 256) Wlds[i] = W[i];

    const float4* y4 = (const float4*)y;
    #pragma unroll
    for (int k = 0; k < 4; ++k) {
        int f = tid + k * 256;            // float4 slot in tile: 0..1023
        int row = f >> 4;                 // 16 float4 per row
        int c4 = (f & 15) << 2;
        float4 val = make_float4(0.f, 0.f, 0.f, 0.f);
        if (r0 + row < N) val = y4[(size_t)(r0 + row) * 16 + (f & 15)];
        A[row][c4 + 0] = val.x; A[row][c4 + 1] = val.y;
        A[row][c4 + 2] = val.z; A[row][c4 + 3] = val.w;
    }
    __syncthreads();

    int wu = __builtin_amdgcn_readfirstlane(tid >> 6);
    int lane = tid & 63;
    int c0 = wu * 16;
    float acc[16];
    #pragma unroll
    for (int cc = 0; cc < 16; ++cc) acc[cc] = bvec[c0 + cc];

    #pragma unroll 8
    for (int k = 0; k < 64; ++k) {
        float a = A[lane][k];                    // (lane+k)%32 -> 2-way, free
        const float* wr = &Wlds[k * DFEAT + c0]; // wave-uniform LDS broadcast
        #pragma unroll
        for (int cc = 0; cc < 16; ++cc) acc[cc] = fmaf(a, wr[cc], acc[cc]);
    }

    int r = r0 + lane;
    if (r < N) {
        float4* yp = (float4*)&y[(size_t)r * DFEAT + c0];
        yp[0] = make_float4(acc[0],  acc[1],  acc[2],  acc[3]);
        yp[1] = make_float4(acc[4],  acc[5],  acc[6],  acc[7]);
        yp[2] = make_float4(acc[8],  acc[9],  acc[10], acc[11]);
        yp[3] = make_float4(acc[12], acc[13], acc[14], acc[15]);
    } else {
        #pragma unroll
        for (int cc = 0; cc < 16; ++cc) acc[cc] = 0.f;   // pad rows: 0 into BN stats
    }

    #pragma unroll
    for (int cc = 0; cc < 16; ++cc) {
        float v1 = acc[cc];
        float v2 = acc[cc] * acc[cc];
        for (int off = 32; off > 0; off >>= 1) {
            v1 += __shfl_down(v1, off);
            v2 += __shfl_down(v2, off);
        }
        if (lane == 0) {
            atomicAdd(&sums[c0 + cc], v1);
            atomicAdd(&sumsq[c0 + cc], v2);
        }
    }
}

// ---------------- BN (batch stats) + ReLU + residual, float4, in place on y ----------------
__global__ void bn_relu_res_kernel(const float* __restrict__ x,
                                   const float* __restrict__ sums,
                                   const float* __restrict__ sumsq,
                                   const float* __restrict__ gamma,
                                   const float* __restrict__ beta,
                                   float* __restrict__ y, int n4, float inv_n) {
    int i = blockIdx.x * blockDim.x + threadIdx.x;   // float4 index
    if (i < n4) {
        int c0 = (i << 2) & (DFEAT - 1);
        float4 yv = ((const float4*)y)[i];
        float4 xv = ((const float4*)x)[i];
        float o[4] = {yv.x, yv.y, yv.z, yv.w};
        float xi[4] = {xv.x, xv.y, xv.z, xv.w};
        #pragma unroll
        for (int k = 0; k < 4; ++k) {
            int c = c0 + k;
            float mean = sums[c] * inv_n;
            float var = sumsq[c] * inv_n - mean * mean;
            float inv = rsqrtf(var + EPSBN);
            float v = (o[k] - mean) * inv * gamma[c] + beta[c];
            o[k] = xi[k] + fmaxf(v, 0.f);
        }
        ((float4*)y)[i] = make_float4(o[0], o[1], o[2], o[3]);
    }
}

extern "C" void kernel_launch(void* const* d_in, const int* in_sizes, int n_in,
                              void* d_out, int out_size, void* d_ws, size_t ws_size,
                              hipStream_t stream) {
    const float* x     = (const float*)d_in[0];
    const int*   src   = (const int*)d_in[1];
    const int*   dst   = (const int*)d_in[2];
    const float* W     = (const float*)d_in[3];
    const float* bvec  = (const float*)d_in[4];
    const float* gamma = (const float*)d_in[5];
    const float* beta  = (const float*)d_in[6];
    float* out = (float*)d_out;   // used as agg, then y, in place

    const int n_nodes = in_sizes[0] / DFEAT;
    const int E = in_sizes[1];
    const int NB = (n_nodes + SCB - 1) / SCB;

    // workspace: epack first (8B align), then zeroable int block, then row_start/bsum
    char* wsb = (char*)d_ws;
    int2* epack      = (int2*)wsb;                        // E
    int*  deg_out_i  = (int*)(wsb + (size_t)E * 8);       // N   <- zeroed
    int*  deg_in_i   = deg_out_i + n_nodes;               // N   <- zeroed
    int*  cursor     = deg_in_i + n_nodes;                // N   <- zeroed
    float* sums      = (float*)(cursor + n_nodes);        // 64  <- zeroed
    float* sumsq     = sums + DFEAT;                      // 64  <- zeroed
    int*  row_start  = (int*)(sumsq + DFEAT);             // N+1
    int*  bsum       = row_start + n_nodes + 1;           // NB (<=64)

    size_t zero_bytes = (3 * (size_t)n_nodes + 2 * DFEAT) * sizeof(int);
    hipMemsetAsync(deg_out_i, 0, zero_bytes, stream);

    hist_kernel<<<(E + 255) / 256, 256, 0, stream>>>(src, dst, deg_out_i, deg_in_i, E);

    scan1_kernel<<<NB, 256, 0, stream>>>(deg_in_i, bsum, n_nodes);
    scan2_kernel<<<1, 64, 0, stream>>>(bsum, row_start, NB, n_nodes);
    scan3_kernel<<<NB, 256, 0, stream>>>(deg_in_i, bsum, row_start, n_nodes);

    fill_kernel<<<(E + 255) / 256, 256, 0, stream>>>(src, dst, deg_out_i, row_start,
                                                     cursor, epack, E);

    spmm_kernel<<<(n_nodes + 3) / 4, 256, 0, stream>>>(x, row_start, epack, out, n_nodes);

    int ntiles = (n_nodes + 63) / 64;
    gemm_bn_kernel<<<ntiles, 256, 0, stream>>>(W, bvec, out, sums, sumsq, n_nodes);

    int n4 = n_nodes * DFEAT / 4;
    bn_relu_res_kernel<<<(n4 + 255) / 256, 256, 0, stream>>>(
        x, sums, sumsq, gamma, beta, out, n4, 1.0f / (float)n_nodes);
}

// Round 6
// 430.044 us; speedup vs baseline: 2.2901x; 2.2901x over previous
//
#include <hip/hip_runtime.h>
#include <hip/hip_bf16.h>

#define DFEAT 64
#define EPSBN 1e-5f
#define SCB 2048   // elements per scan block (256 threads x 8)

// ---------------- degree histogram (int atomics) ----------------
__global__ void hist_kernel(const int* __restrict__ src, const int* __restrict__ dst,
                            int* __restrict__ deg_out, int* __restrict__ deg_in, int E) {
    int e = blockIdx.x * blockDim.x + threadIdx.x;
    if (e < E) {
        atomicAdd(&deg_out[src[e]], 1);
        atomicAdd(&deg_in[dst[e]], 1);
    }
}

// ---------------- scan pass 1: per-block sums of deg_in ----------------
__global__ void scan1_kernel(const int* __restrict__ deg, int* __restrict__ bsum, int N) {
    __shared__ int red[256];
    int t = threadIdx.x;
    int base = blockIdx.x * SCB + t * 8;
    int s = 0;
    #pragma unroll
    for (int j = 0; j < 8; ++j) { int idx = base + j; if (idx < N) s += deg[idx]; }
    red[t] = s;
    __syncthreads();
    for (int d = 128; d > 0; d >>= 1) { if (t < d) red[t] += red[t + d]; __syncthreads(); }
    if (t == 0) bsum[blockIdx.x] = red[0];
}

// ---------------- scan pass 2: one-wave shuffle exclusive scan (NB <= 64) ----------------
__global__ void scan2_kernel(int* __restrict__ bsum, int* __restrict__ row_start, int NB, int N) {
    int lane = threadIdx.x & 63;
    int v = (lane < NB) ? bsum[lane] : 0;
    int incl = v;
    #pragma unroll
    for (int off = 1; off < 64; off <<= 1) {
        int t = __shfl_up(incl, off);
        if (lane >= off) incl += t;
    }
    if (lane < NB) bsum[lane] = incl - v;
    if (lane == 63) row_start[N] = incl;   // total == E
}

// ---------------- scan pass 3: full exclusive scan -> row_start ----------------
__global__ void scan3_kernel(const int* __restrict__ deg, const int* __restrict__ bsum,
                             int* __restrict__ row_start, int N) {
    __shared__ int sc[256];
    int t = threadIdx.x;
    int base = blockIdx.x * SCB + t * 8;
    int v[8], ex[8];
    int s = 0;
    #pragma unroll
    for (int j = 0; j < 8; ++j) {
        int idx = base + j;
        v[j] = (idx < N) ? deg[idx] : 0;
        ex[j] = s;
        s += v[j];
    }
    sc[t] = s;
    __syncthreads();
    for (int d = 1; d < 256; d <<= 1) {
        int vv = (t >= d) ? sc[t - d] : 0;
        __syncthreads();
        sc[t] += vv;
        __syncthreads();
    }
    int toff = sc[t] - s + bsum[blockIdx.x];
    #pragma unroll
    for (int j = 0; j < 8; ++j) {
        int idx = base + j;
        if (idx < N) row_start[idx] = toff + ex[j];
    }
}

// ---------------- counting-sort edges by dst, pack (src, coef) ----------------
__global__ void fill_kernel(const int* __restrict__ src, const int* __restrict__ dst,
                            const int* __restrict__ deg_out, const int* __restrict__ row_start,
                            int* __restrict__ cursor, int2* __restrict__ epack, int E) {
    int e = blockIdx.x * blockDim.x + threadIdx.x;
    if (e < E) {
        int d = dst[e], s = src[e];
        int pos = atomicAdd(&cursor[d], 1);
        float coef = rsqrtf((float)max(deg_out[s], 1));
        epack[row_start[d] + pos] = make_int2(s, __float_as_int(coef));
    }
}

// ---------------- SpMM: ONE dst row per wave, massive TLP, no atomics ----------------
__global__ __launch_bounds__(256, 6) void spmm_kernel(
        const float* __restrict__ x, const int* __restrict__ row_start,
        const int2* __restrict__ epack, float* __restrict__ agg, int N) {
    int lane = threadIdx.x & 63;
    int r = blockIdx.x * 4 + (threadIdx.x >> 6);
    if (r >= N) return;
    int beg = row_start[r];
    int end = row_start[r + 1];
    float acc = 0.f;
    for (int cb = beg; cb < end; cb += 64) {
        int take = min(64, end - cb);
        int2 p = (lane < take) ? epack[cb + lane] : make_int2(0, 0);
        int j = 0;
        for (; j + 8 <= take; j += 8) {
            int sj[8]; float cj[8], v[8];
            #pragma unroll
            for (int u = 0; u < 8; ++u) {
                sj[u] = __shfl(p.x, j + u);
                cj[u] = __int_as_float(__shfl(p.y, j + u));
            }
            #pragma unroll
            for (int u = 0; u < 8; ++u) v[u] = x[(size_t)sj[u] * DFEAT + lane];
            #pragma unroll
            for (int u = 0; u < 8; ++u) acc = fmaf(v[u], cj[u], acc);
        }
        for (; j < take; ++j) {
            int s = __shfl(p.x, j);
            float c = __int_as_float(__shfl(p.y, j));
            acc = fmaf(x[(size_t)s * DFEAT + lane], c, acc);
        }
    }
    acc *= rsqrtf((float)max(end - beg, 1));   // norm_dst
    agg[(size_t)r * DFEAT + lane] = acc;       // exclusive row: plain coalesced store
}

// ---------------- GEMM (in place on y==agg) + BN stats ----------------
// one block = one 64-row tile. BN stats: per-block LDS reduce, then ONE
// wave-wide atomic instruction per block (64 consecutive addresses — HW
// batches per line; the round-5 lane==0 scalar-atomic pattern serialized
// 100K atomics onto 8 lines -> 624 us).
__global__ __launch_bounds__(256) void gemm_bn_kernel(
        const float* __restrict__ W, const float* __restrict__ bvec,
        float* __restrict__ y, float* __restrict__ sums, float* __restrict__ sumsq,
        int N) {
    __shared__ float Wlds[DFEAT * DFEAT];
    __shared__ float A[64][65];
    __shared__ float red_s[4][DFEAT];
    __shared__ float red_q[4][DFEAT];
    int tid = threadIdx.x;
    int r0 = blockIdx.x * 64;

    for (int i = tid; i < DFEAT * DFEAT; i += 256) Wlds[i] = W[i];

    const float4* y4 = (const float4*)y;
    #pragma unroll
    for (int k = 0; k < 4; ++k) {
        int f = tid + k * 256;            // float4 slot in tile: 0..1023
        int row = f >> 4;                 // 16 float4 per row
        int c4 = (f & 15) << 2;
        float4 val = make_float4(0.f, 0.f, 0.f, 0.f);
        if (r0 + row < N) val = y4[(size_t)(r0 + row) * 16 + (f & 15)];
        A[row][c4 + 0] = val.x; A[row][c4 + 1] = val.y;
        A[row][c4 + 2] = val.z; A[row][c4 + 3] = val.w;
    }
    __syncthreads();

    int w = tid >> 6;
    int wu = __builtin_amdgcn_readfirstlane(w);
    int lane = tid & 63;
    int c0 = wu * 16;
    float acc[16];
    #pragma unroll
    for (int cc = 0; cc < 16; ++cc) acc[cc] = bvec[c0 + cc];

    #pragma unroll 8
    for (int k = 0; k < 64; ++k) {
        float a = A[lane][k];                    // (lane+k)%32 -> 2-way, free
        const float* wr = &Wlds[k * DFEAT + c0]; // wave-uniform LDS broadcast
        #pragma unroll
        for (int cc = 0; cc < 16; ++cc) acc[cc] = fmaf(a, wr[cc], acc[cc]);
    }

    int r = r0 + lane;
    if (r < N) {
        float4* yp = (float4*)&y[(size_t)r * DFEAT + c0];
        yp[0] = make_float4(acc[0],  acc[1],  acc[2],  acc[3]);
        yp[1] = make_float4(acc[4],  acc[5],  acc[6],  acc[7]);
        yp[2] = make_float4(acc[8],  acc[9],  acc[10], acc[11]);
        yp[3] = make_float4(acc[12], acc[13], acc[14], acc[15]);
    } else {
        #pragma unroll
        for (int cc = 0; cc < 16; ++cc) acc[cc] = 0.f;   // pad rows: 0 into BN stats
    }

    // per-wave shuffle reduce over lanes (= rows), park 16 col-partials in LDS
    #pragma unroll
    for (int cc = 0; cc < 16; ++cc) {
        float v1 = acc[cc];
        float v2 = acc[cc] * acc[cc];
        for (int off = 32; off > 0; off >>= 1) {
            v1 += __shfl_down(v1, off);
            v2 += __shfl_down(v2, off);
        }
        if (lane == 0) {
            red_s[w][c0 + cc] = v1;   // col c is owned by wave c>>4 only
            red_q[w][c0 + cc] = v2;
        }
    }
    __syncthreads();
    if (w == 0) {
        // one wave-wide atomic instruction: 64 lanes -> 64 consecutive floats
        atomicAdd(&sums[lane],  red_s[lane >> 4][lane]);
        atomicAdd(&sumsq[lane], red_q[lane >> 4][lane]);
    }
}

// ---------------- BN (batch stats) + ReLU + residual, float4, in place on y ----------------
__global__ void bn_relu_res_kernel(const float* __restrict__ x,
                                   const float* __restrict__ sums,
                                   const float* __restrict__ sumsq,
                                   const float* __restrict__ gamma,
                                   const float* __restrict__ beta,
                                   float* __restrict__ y, int n4, float inv_n) {
    int i = blockIdx.x * blockDim.x + threadIdx.x;   // float4 index
    if (i < n4) {
        int c0 = (i << 2) & (DFEAT - 1);
        float4 yv = ((const float4*)y)[i];
        float4 xv = ((const float4*)x)[i];
        float o[4] = {yv.x, yv.y, yv.z, yv.w};
        float xi[4] = {xv.x, xv.y, xv.z, xv.w};
        #pragma unroll
        for (int k = 0; k < 4; ++k) {
            int c = c0 + k;
            float mean = sums[c] * inv_n;
            float var = sumsq[c] * inv_n - mean * mean;
            float inv = rsqrtf(var + EPSBN);
            float v = (o[k] - mean) * inv * gamma[c] + beta[c];
            o[k] = xi[k] + fmaxf(v, 0.f);
        }
        ((float4*)y)[i] = make_float4(o[0], o[1], o[2], o[3]);
    }
}

extern "C" void kernel_launch(void* const* d_in, const int* in_sizes, int n_in,
                              void* d_out, int out_size, void* d_ws, size_t ws_size,
                              hipStream_t stream) {
    const float* x     = (const float*)d_in[0];
    const int*   src   = (const int*)d_in[1];
    const int*   dst   = (const int*)d_in[2];
    const float* W     = (const float*)d_in[3];
    const float* bvec  = (const float*)d_in[4];
    const float* gamma = (const float*)d_in[5];
    const float* beta  = (const float*)d_in[6];
    float* out = (float*)d_out;   // used as agg, then y, in place

    const int n_nodes = in_sizes[0] / DFEAT;
    const int E = in_sizes[1];
    const int NB = (n_nodes + SCB - 1) / SCB;

    // workspace: epack first (8B align), then zeroable int block, then row_start/bsum
    char* wsb = (char*)d_ws;
    int2* epack      = (int2*)wsb;                        // E
    int*  deg_out_i  = (int*)(wsb + (size_t)E * 8);       // N   <- zeroed
    int*  deg_in_i   = deg_out_i + n_nodes;               // N   <- zeroed
    int*  cursor     = deg_in_i + n_nodes;                // N   <- zeroed
    float* sums      = (float*)(cursor + n_nodes);        // 64  <- zeroed
    float* sumsq     = sums + DFEAT;                      // 64  <- zeroed
    int*  row_start  = (int*)(sumsq + DFEAT);             // N+1
    int*  bsum       = row_start + n_nodes + 1;           // NB (<=64)

    size_t zero_bytes = (3 * (size_t)n_nodes + 2 * DFEAT) * sizeof(int);
    hipMemsetAsync(deg_out_i, 0, zero_bytes, stream);

    hist_kernel<<<(E + 255) / 256, 256, 0, stream>>>(src, dst, deg_out_i, deg_in_i, E);

    scan1_kernel<<<NB, 256, 0, stream>>>(deg_in_i, bsum, n_nodes);
    scan2_kernel<<<1, 64, 0, stream>>>(bsum, row_start, NB, n_nodes);
    scan3_kernel<<<NB, 256, 0, stream>>>(deg_in_i, bsum, row_start, n_nodes);

    fill_kernel<<<(E + 255) / 256, 256, 0, stream>>>(src, dst, deg_out_i, row_start,
                                                     cursor, epack, E);

    spmm_kernel<<<(n_nodes + 3) / 4, 256, 0, stream>>>(x, row_start, epack, out, n_nodes);

    int ntiles = (n_nodes + 63) / 64;
    gemm_bn_kernel<<<ntiles, 256, 0, stream>>>(W, bvec, out, sums, sumsq, n_nodes);

    int n4 = n_nodes * DFEAT / 4;
    bn_relu_res_kernel<<<(n4 + 255) / 256, 256, 0, stream>>>(
        x, sums, sumsq, gamma, beta, out, n4, 1.0f / (float)n_nodes);
}

// Round 7
// 401.959 us; speedup vs baseline: 2.4501x; 1.0699x over previous
//
#include <hip/hip_runtime.h>
#include <hip/hip_bf16.h>

#define DFEAT 64
#define EPSBN 1e-5f
#define SCB 2048   // elements per scan block (256 threads x 8)

// ---------------- degree histogram (int atomics) + dst-rank capture ----------------
// the deg_in atomic's return value IS the edge's rank within its dst row:
// capturing it here makes the fill pass atomic-free (round-6: fill's 1.6M
// cursor atomics paid the ~26G sector-tx/s scattered-atomic ceiling a 2nd time)
__global__ void hist_kernel(const int* __restrict__ src, const int* __restrict__ dst,
                            int* __restrict__ deg_out, int* __restrict__ deg_in,
                            unsigned short* __restrict__ rank, int E) {
    int e = blockIdx.x * blockDim.x + threadIdx.x;
    if (e < E) {
        atomicAdd(&deg_out[src[e]], 1);
        rank[e] = (unsigned short)atomicAdd(&deg_in[dst[e]], 1);
    }
}

// ---------------- scan pass 1: per-block sums of deg_in ----------------
__global__ void scan1_kernel(const int* __restrict__ deg, int* __restrict__ bsum, int N) {
    __shared__ int red[256];
    int t = threadIdx.x;
    int base = blockIdx.x * SCB + t * 8;
    int s = 0;
    #pragma unroll
    for (int j = 0; j < 8; ++j) { int idx = base + j; if (idx < N) s += deg[idx]; }
    red[t] = s;
    __syncthreads();
    for (int d = 128; d > 0; d >>= 1) { if (t < d) red[t] += red[t + d]; __syncthreads(); }
    if (t == 0) bsum[blockIdx.x] = red[0];
}

// ---------------- scan pass 2: one-wave shuffle exclusive scan (NB <= 64) ----------------
__global__ void scan2_kernel(int* __restrict__ bsum, int* __restrict__ row_start, int NB, int N) {
    int lane = threadIdx.x & 63;
    int v = (lane < NB) ? bsum[lane] : 0;
    int incl = v;
    #pragma unroll
    for (int off = 1; off < 64; off <<= 1) {
        int t = __shfl_up(incl, off);
        if (lane >= off) incl += t;
    }
    if (lane < NB) bsum[lane] = incl - v;
    if (lane == 63) row_start[N] = incl;   // total == E
}

// ---------------- scan pass 3: full exclusive scan -> row_start ----------------
__global__ void scan3_kernel(const int* __restrict__ deg, const int* __restrict__ bsum,
                             int* __restrict__ row_start, int N) {
    __shared__ int sc[256];
    int t = threadIdx.x;
    int base = blockIdx.x * SCB + t * 8;
    int v[8], ex[8];
    int s = 0;
    #pragma unroll
    for (int j = 0; j < 8; ++j) {
        int idx = base + j;
        v[j] = (idx < N) ? deg[idx] : 0;
        ex[j] = s;
        s += v[j];
    }
    sc[t] = s;
    __syncthreads();
    for (int d = 1; d < 256; d <<= 1) {
        int vv = (t >= d) ? sc[t - d] : 0;
        __syncthreads();
        sc[t] += vv;
        __syncthreads();
    }
    int toff = sc[t] - s + bsum[blockIdx.x];
    #pragma unroll
    for (int j = 0; j < 8; ++j) {
        int idx = base + j;
        if (idx < N) row_start[idx] = toff + ex[j];
    }
}

// ---------------- place edges at row_start[dst]+rank (NO atomics) ----------------
__global__ void fill_kernel(const int* __restrict__ src, const int* __restrict__ dst,
                            const unsigned short* __restrict__ rank,
                            const int* __restrict__ deg_out, const int* __restrict__ row_start,
                            int2* __restrict__ epack, int E) {
    int e = blockIdx.x * blockDim.x + threadIdx.x;
    if (e < E) {
        int d = dst[e], s = src[e];
        float coef = rsqrtf((float)max(deg_out[s], 1));
        epack[row_start[d] + (int)rank[e]] = make_int2(s, __float_as_int(coef));
    }
}

// ---------------- SpMM: ONE dst row per wave, massive TLP, no atomics ----------------
__global__ __launch_bounds__(256, 6) void spmm_kernel(
        const float* __restrict__ x, const int* __restrict__ row_start,
        const int2* __restrict__ epack, float* __restrict__ agg, int N) {
    int lane = threadIdx.x & 63;
    int r = blockIdx.x * 4 + (threadIdx.x >> 6);
    if (r >= N) return;
    int beg = row_start[r];
    int end = row_start[r + 1];
    float acc = 0.f;
    for (int cb = beg; cb < end; cb += 64) {
        int take = min(64, end - cb);
        int2 p = (lane < take) ? epack[cb + lane] : make_int2(0, 0);
        int j = 0;
        for (; j + 8 <= take; j += 8) {
            int sj[8]; float cj[8], v[8];
            #pragma unroll
            for (int u = 0; u < 8; ++u) {
                sj[u] = __shfl(p.x, j + u);
                cj[u] = __int_as_float(__shfl(p.y, j + u));
            }
            #pragma unroll
            for (int u = 0; u < 8; ++u) v[u] = x[(size_t)sj[u] * DFEAT + lane];
            #pragma unroll
            for (int u = 0; u < 8; ++u) acc = fmaf(v[u], cj[u], acc);
        }
        for (; j < take; ++j) {
            int s = __shfl(p.x, j);
            float c = __int_as_float(__shfl(p.y, j));
            acc = fmaf(x[(size_t)s * DFEAT + lane], c, acc);
        }
    }
    acc *= rsqrtf((float)max(end - beg, 1));   // norm_dst
    agg[(size_t)r * DFEAT + lane] = acc;       // exclusive row: plain coalesced store
}

// ---------------- GEMM (in place on y==agg) + BN stats ----------------
// BN stats: per-block LDS reduce, then ONE wave-wide atomic instruction per
// block (64 consecutive addresses -> HW batches per line).
__global__ __launch_bounds__(256) void gemm_bn_kernel(
        const float* __restrict__ W, const float* __restrict__ bvec,
        float* __restrict__ y, float* __restrict__ sums, float* __restrict__ sumsq,
        int N) {
    __shared__ float Wlds[DFEAT * DFEAT];
    __shared__ float A[64][65];
    __shared__ float red_s[4][DFEAT];
    __shared__ float red_q[4][DFEAT];
    int tid = threadIdx.x;
    int r0 = blockIdx.x * 64;

    for (int i = tid; i < DFEAT * DFEAT; i += 256) Wlds[i] = W[i];

    const float4* y4 = (const float4*)y;
    #pragma unroll
    for (int k = 0; k < 4; ++k) {
        int f = tid + k * 256;            // float4 slot in tile: 0..1023
        int row = f >> 4;                 // 16 float4 per row
        int c4 = (f & 15) << 2;
        float4 val = make_float4(0.f, 0.f, 0.f, 0.f);
        if (r0 + row < N) val = y4[(size_t)(r0 + row) * 16 + (f & 15)];
        A[row][c4 + 0] = val.x; A[row][c4 + 1] = val.y;
        A[row][c4 + 2] = val.z; A[row][c4 + 3] = val.w;
    }
    __syncthreads();

    int w = tid >> 6;
    int wu = __builtin_amdgcn_readfirstlane(w);
    int lane = tid & 63;
    int c0 = wu * 16;
    float acc[16];
    #pragma unroll
    for (int cc = 0; cc < 16; ++cc) acc[cc] = bvec[c0 + cc];

    #pragma unroll 8
    for (int k = 0; k < 64; ++k) {
        float a = A[lane][k];                    // (lane+k)%32 -> 2-way, free
        const float* wr = &Wlds[k * DFEAT + c0]; // wave-uniform LDS broadcast
        #pragma unroll
        for (int cc = 0; cc < 16; ++cc) acc[cc] = fmaf(a, wr[cc], acc[cc]);
    }

    int r = r0 + lane;
    if (r < N) {
        float4* yp = (float4*)&y[(size_t)r * DFEAT + c0];
        yp[0] = make_float4(acc[0],  acc[1],  acc[2],  acc[3]);
        yp[1] = make_float4(acc[4],  acc[5],  acc[6],  acc[7]);
        yp[2] = make_float4(acc[8],  acc[9],  acc[10], acc[11]);
        yp[3] = make_float4(acc[12], acc[13], acc[14], acc[15]);
    } else {
        #pragma unroll
        for (int cc = 0; cc < 16; ++cc) acc[cc] = 0.f;   // pad rows: 0 into BN stats
    }

    #pragma unroll
    for (int cc = 0; cc < 16; ++cc) {
        float v1 = acc[cc];
        float v2 = acc[cc] * acc[cc];
        for (int off = 32; off > 0; off >>= 1) {
            v1 += __shfl_down(v1, off);
            v2 += __shfl_down(v2, off);
        }
        if (lane == 0) {
            red_s[w][c0 + cc] = v1;   // col c is owned by wave c>>4 only
            red_q[w][c0 + cc] = v2;
        }
    }
    __syncthreads();
    if (w == 0) {
        // one wave-wide atomic instruction: 64 lanes -> 64 consecutive floats
        atomicAdd(&sums[lane],  red_s[lane >> 4][lane]);
        atomicAdd(&sumsq[lane], red_q[lane >> 4][lane]);
    }
}

// ---------------- BN (batch stats) + ReLU + residual, float4, in place on y ----------------
__global__ void bn_relu_res_kernel(const float* __restrict__ x,
                                   const float* __restrict__ sums,
                                   const float* __restrict__ sumsq,
                                   const float* __restrict__ gamma,
                                   const float* __restrict__ beta,
                                   float* __restrict__ y, int n4, float inv_n) {
    int i = blockIdx.x * blockDim.x + threadIdx.x;   // float4 index
    if (i < n4) {
        int c0 = (i << 2) & (DFEAT - 1);
        float4 yv = ((const float4*)y)[i];
        float4 xv = ((const float4*)x)[i];
        float o[4] = {yv.x, yv.y, yv.z, yv.w};
        float xi[4] = {xv.x, xv.y, xv.z, xv.w};
        #pragma unroll
        for (int k = 0; k < 4; ++k) {
            int c = c0 + k;
            float mean = sums[c] * inv_n;
            float var = sumsq[c] * inv_n - mean * mean;
            float inv = rsqrtf(var + EPSBN);
            float v = (o[k] - mean) * inv * gamma[c] + beta[c];
            o[k] = xi[k] + fmaxf(v, 0.f);
        }
        ((float4*)y)[i] = make_float4(o[0], o[1], o[2], o[3]);
    }
}

extern "C" void kernel_launch(void* const* d_in, const int* in_sizes, int n_in,
                              void* d_out, int out_size, void* d_ws, size_t ws_size,
                              hipStream_t stream) {
    const float* x     = (const float*)d_in[0];
    const int*   src   = (const int*)d_in[1];
    const int*   dst   = (const int*)d_in[2];
    const float* W     = (const float*)d_in[3];
    const float* bvec  = (const float*)d_in[4];
    const float* gamma = (const float*)d_in[5];
    const float* beta  = (const float*)d_in[6];
    float* out = (float*)d_out;   // used as agg, then y, in place

    const int n_nodes = in_sizes[0] / DFEAT;
    const int E = in_sizes[1];
    const int NB = (n_nodes + SCB - 1) / SCB;

    // workspace: epack (8B align) | rank (E u16) | zeroable ints | row_start | bsum
    char* wsb = (char*)d_ws;
    int2* epack      = (int2*)wsb;                                   // E
    unsigned short* rank = (unsigned short*)(wsb + (size_t)E * 8);   // E
    int*  deg_out_i  = (int*)(wsb + (size_t)E * 8 + (size_t)E * 2);  // N   <- zeroed
    int*  deg_in_i   = deg_out_i + n_nodes;                          // N   <- zeroed
    float* sums      = (float*)(deg_in_i + n_nodes);                 // 64  <- zeroed
    float* sumsq     = sums + DFEAT;                                 // 64  <- zeroed
    int*  row_start  = (int*)(sumsq + DFEAT);                        // N+1
    int*  bsum       = row_start + n_nodes + 1;                      // NB (<=64)

    size_t zero_bytes = (2 * (size_t)n_nodes + 2 * DFEAT) * sizeof(int);
    hipMemsetAsync(deg_out_i, 0, zero_bytes, stream);

    hist_kernel<<<(E + 255) / 256, 256, 0, stream>>>(src, dst, deg_out_i, deg_in_i,
                                                     rank, E);

    scan1_kernel<<<NB, 256, 0, stream>>>(deg_in_i, bsum, n_nodes);
    scan2_kernel<<<1, 64, 0, stream>>>(bsum, row_start, NB, n_nodes);
    scan3_kernel<<<NB, 256, 0, stream>>>(deg_in_i, bsum, row_start, n_nodes);

    fill_kernel<<<(E + 255) / 256, 256, 0, stream>>>(src, dst, rank, deg_out_i,
                                                     row_start, epack, E);

    spmm_kernel<<<(n_nodes + 3) / 4, 256, 0, stream>>>(x, row_start, epack, out, n_nodes);

    int ntiles = (n_nodes + 63) / 64;
    gemm_bn_kernel<<<ntiles, 256, 0, stream>>>(W, bvec, out, sums, sumsq, n_nodes);

    int n4 = n_nodes * DFEAT / 4;
    bn_relu_res_kernel<<<(n4 + 255) / 256, 256, 0, stream>>>(
        x, sums, sumsq, gamma, beta, out, n4, 1.0f / (float)n_nodes);
}

// Round 8
// 363.099 us; speedup vs baseline: 2.7123x; 1.1070x over previous
//
#include <hip/hip_runtime.h>
#include <hip/hip_bf16.h>

#define DFEAT 64
#define EPSBN 1e-5f
#define SCB 2048      // elements per scan block (256 threads x 8)
#define CHUNK_LG 16
#define CHUNK (1 << CHUNK_LG)   // 65536 edges per chunk
#define RNG 8192      // nodes per partition (2 x 32KB LDS histograms)

// ---------------- LDS-privatized dual histogram + chunk-local rank ----------------
// block (c,p): scan edge chunk c, count src/dst hits in node range p via LDS
// atomics (no global scattered atomics -> off the ~26G sector-tx/s ceiling that
// capped rounds 6/7). dst LDS-atomic return = chunk-local rank (coalesced u16
// store). Counts flush: deg_out via CONTIGUOUS wave-wide global atomics (cheap,
// round-6 evidence); per-chunk dst counts to cnt matrix for the column scan.
__global__ __launch_bounds__(256) void hist2d_kernel(
        const int* __restrict__ src, const int* __restrict__ dst,
        unsigned short* __restrict__ lrank, unsigned short* __restrict__ cnt,
        int* __restrict__ deg_out, int E, int N, int N_pad) {
    __shared__ int ho[RNG];
    __shared__ int hd[RNG];
    int tid = threadIdx.x;
    int c = blockIdx.x, p = blockIdx.y;
    int nbeg = p * RNG;
    for (int i = tid; i < RNG; i += 256) { ho[i] = 0; hd[i] = 0; }
    __syncthreads();

    int ebeg = c << CHUNK_LG;
    int eend = min(ebeg + CHUNK, E);
    for (int e = ebeg + tid; e < eend; e += 256) {
        int s = src[e];
        int d = dst[e];
        unsigned int so = (unsigned int)(s - nbeg);
        unsigned int dof = (unsigned int)(d - nbeg);
        if (so < RNG) atomicAdd(&ho[so], 1);
        if (dof < RNG) lrank[e] = (unsigned short)atomicAdd(&hd[dof], 1);
    }
    __syncthreads();

    for (int i = tid; i < RNG; i += 256) {
        int n = nbeg + i;
        if (n < N) {
            if (ho[i]) atomicAdd(&deg_out[n], ho[i]);   // contiguous lanes -> batched
            cnt[(size_t)c * N_pad + n] = (unsigned short)hd[i];
        }
    }
}

// ---------------- column scan: per-node exclusive prefix over chunks ----------------
// cnt[c][n] -> (in place) #edges with dst n in chunks < c; total -> deg_in[n]
__global__ void colscan_kernel(unsigned short* __restrict__ cnt,
                               int* __restrict__ deg_in, int N, int N_pad, int C) {
    int n = blockIdx.x * blockDim.x + threadIdx.x;
    if (n >= N) return;
    int run = 0;
    for (int c = 0; c < C; ++c) {
        size_t idx = (size_t)c * N_pad + n;
        int v = cnt[idx];
        cnt[idx] = (unsigned short)run;
        run += v;
    }
    deg_in[n] = run;
}

// ---------------- scan pass 1: per-block sums of deg_in ----------------
__global__ void scan1_kernel(const int* __restrict__ deg, int* __restrict__ bsum, int N) {
    __shared__ int red[256];
    int t = threadIdx.x;
    int base = blockIdx.x * SCB + t * 8;
    int s = 0;
    #pragma unroll
    for (int j = 0; j < 8; ++j) { int idx = base + j; if (idx < N) s += deg[idx]; }
    red[t] = s;
    __syncthreads();
    for (int d = 128; d > 0; d >>= 1) { if (t < d) red[t] += red[t + d]; __syncthreads(); }
    if (t == 0) bsum[blockIdx.x] = red[0];
}

// ---------------- scan pass 2: one-wave shuffle exclusive scan (NB <= 64) ----------------
__global__ void scan2_kernel(int* __restrict__ bsum, int* __restrict__ row_start, int NB, int N) {
    int lane = threadIdx.x & 63;
    int v = (lane < NB) ? bsum[lane] : 0;
    int incl = v;
    #pragma unroll
    for (int off = 1; off < 64; off <<= 1) {
        int t = __shfl_up(incl, off);
        if (lane >= off) incl += t;
    }
    if (lane < NB) bsum[lane] = incl - v;
    if (lane == 63) row_start[N] = incl;   // total == E
}

// ---------------- scan pass 3: full exclusive scan -> row_start ----------------
__global__ void scan3_kernel(const int* __restrict__ deg, const int* __restrict__ bsum,
                             int* __restrict__ row_start, int N) {
    __shared__ int sc[256];
    int t = threadIdx.x;
    int base = blockIdx.x * SCB + t * 8;
    int v[8], ex[8];
    int s = 0;
    #pragma unroll
    for (int j = 0; j < 8; ++j) {
        int idx = base + j;
        v[j] = (idx < N) ? deg[idx] : 0;
        ex[j] = s;
        s += v[j];
    }
    sc[t] = s;
    __syncthreads();
    for (int d = 1; d < 256; d <<= 1) {
        int vv = (t >= d) ? sc[t - d] : 0;
        __syncthreads();
        sc[t] += vv;
        __syncthreads();
    }
    int toff = sc[t] - s + bsum[blockIdx.x];
    #pragma unroll
    for (int j = 0; j < 8; ++j) {
        int idx = base + j;
        if (idx < N) row_start[idx] = toff + ex[j];
    }
}

// ---------------- place edges: slot = row_start[d] + pref[c][d] + lrank[e] ----------------
__global__ void fill_kernel(const int* __restrict__ src, const int* __restrict__ dst,
                            const unsigned short* __restrict__ lrank,
                            const unsigned short* __restrict__ cnt,
                            const int* __restrict__ deg_out, const int* __restrict__ row_start,
                            int2* __restrict__ epack, int E, int N_pad) {
    int e = blockIdx.x * blockDim.x + threadIdx.x;
    if (e < E) {
        int d = dst[e], s = src[e];
        int c = e >> CHUNK_LG;
        float coef = rsqrtf((float)max(deg_out[s], 1));
        int slot = row_start[d] + (int)cnt[(size_t)c * N_pad + d] + (int)lrank[e];
        epack[slot] = make_int2(s, __float_as_int(coef));
    }
}

// ---------------- SpMM: ONE dst row per wave, massive TLP, no atomics ----------------
__global__ __launch_bounds__(256, 6) void spmm_kernel(
        const float* __restrict__ x, const int* __restrict__ row_start,
        const int2* __restrict__ epack, float* __restrict__ agg, int N) {
    int lane = threadIdx.x & 63;
    int r = blockIdx.x * 4 + (threadIdx.x >> 6);
    if (r >= N) return;
    int beg = row_start[r];
    int end = row_start[r + 1];
    float acc = 0.f;
    for (int cb = beg; cb < end; cb += 64) {
        int take = min(64, end - cb);
        int2 p = (lane < take) ? epack[cb + lane] : make_int2(0, 0);
        int j = 0;
        for (; j + 8 <= take; j += 8) {
            int sj[8]; float cj[8], v[8];
            #pragma unroll
            for (int u = 0; u < 8; ++u) {
                sj[u] = __shfl(p.x, j + u);
                cj[u] = __int_as_float(__shfl(p.y, j + u));
            }
            #pragma unroll
            for (int u = 0; u < 8; ++u) v[u] = x[(size_t)sj[u] * DFEAT + lane];
            #pragma unroll
            for (int u = 0; u < 8; ++u) acc = fmaf(v[u], cj[u], acc);
        }
        for (; j < take; ++j) {
            int s = __shfl(p.x, j);
            float c = __int_as_float(__shfl(p.y, j));
            acc = fmaf(x[(size_t)s * DFEAT + lane], c, acc);
        }
    }
    acc *= rsqrtf((float)max(end - beg, 1));   // norm_dst
    agg[(size_t)r * DFEAT + lane] = acc;       // exclusive row: plain coalesced store
}

// ---------------- GEMM (in place on y==agg) + BN stats ----------------
__global__ __launch_bounds__(256) void gemm_bn_kernel(
        const float* __restrict__ W, const float* __restrict__ bvec,
        float* __restrict__ y, float* __restrict__ sums, float* __restrict__ sumsq,
        int N) {
    __shared__ float Wlds[DFEAT * DFEAT];
    __shared__ float A[64][65];
    __shared__ float red_s[4][DFEAT];
    __shared__ float red_q[4][DFEAT];
    int tid = threadIdx.x;
    int r0 = blockIdx.x * 64;

    for (int i = tid; i < DFEAT * DFEAT; i += 256) Wlds[i] = W[i];

    const float4* y4 = (const float4*)y;
    #pragma unroll
    for (int k = 0; k < 4; ++k) {
        int f = tid + k * 256;            // float4 slot in tile: 0..1023
        int row = f >> 4;                 // 16 float4 per row
        int c4 = (f & 15) << 2;
        float4 val = make_float4(0.f, 0.f, 0.f, 0.f);
        if (r0 + row < N) val = y4[(size_t)(r0 + row) * 16 + (f & 15)];
        A[row][c4 + 0] = val.x; A[row][c4 + 1] = val.y;
        A[row][c4 + 2] = val.z; A[row][c4 + 3] = val.w;
    }
    __syncthreads();

    int w = tid >> 6;
    int wu = __builtin_amdgcn_readfirstlane(w);
    int lane = tid & 63;
    int c0 = wu * 16;
    float acc[16];
    #pragma unroll
    for (int cc = 0; cc < 16; ++cc) acc[cc] = bvec[c0 + cc];

    #pragma unroll 8
    for (int k = 0; k < 64; ++k) {
        float a = A[lane][k];                    // (lane+k)%32 -> 2-way, free
        const float* wr = &Wlds[k * DFEAT + c0]; // wave-uniform LDS broadcast
        #pragma unroll
        for (int cc = 0; cc < 16; ++cc) acc[cc] = fmaf(a, wr[cc], acc[cc]);
    }

    int r = r0 + lane;
    if (r < N) {
        float4* yp = (float4*)&y[(size_t)r * DFEAT + c0];
        yp[0] = make_float4(acc[0],  acc[1],  acc[2],  acc[3]);
        yp[1] = make_float4(acc[4],  acc[5],  acc[6],  acc[7]);
        yp[2] = make_float4(acc[8],  acc[9],  acc[10], acc[11]);
        yp[3] = make_float4(acc[12], acc[13], acc[14], acc[15]);
    } else {
        #pragma unroll
        for (int cc = 0; cc < 16; ++cc) acc[cc] = 0.f;   // pad rows: 0 into BN stats
    }

    #pragma unroll
    for (int cc = 0; cc < 16; ++cc) {
        float v1 = acc[cc];
        float v2 = acc[cc] * acc[cc];
        for (int off = 32; off > 0; off >>= 1) {
            v1 += __shfl_down(v1, off);
            v2 += __shfl_down(v2, off);
        }
        if (lane == 0) {
            red_s[w][c0 + cc] = v1;   // col c is owned by wave c>>4 only
            red_q[w][c0 + cc] = v2;
        }
    }
    __syncthreads();
    if (w == 0) {
        // one wave-wide atomic instruction: 64 lanes -> 64 consecutive floats
        atomicAdd(&sums[lane],  red_s[lane >> 4][lane]);
        atomicAdd(&sumsq[lane], red_q[lane >> 4][lane]);
    }
}

// ---------------- BN (batch stats) + ReLU + residual, float4, in place on y ----------------
__global__ void bn_relu_res_kernel(const float* __restrict__ x,
                                   const float* __restrict__ sums,
                                   const float* __restrict__ sumsq,
                                   const float* __restrict__ gamma,
                                   const float* __restrict__ beta,
                                   float* __restrict__ y, int n4, float inv_n) {
    int i = blockIdx.x * blockDim.x + threadIdx.x;   // float4 index
    if (i < n4) {
        int c0 = (i << 2) & (DFEAT - 1);
        float4 yv = ((const float4*)y)[i];
        float4 xv = ((const float4*)x)[i];
        float o[4] = {yv.x, yv.y, yv.z, yv.w};
        float xi[4] = {xv.x, xv.y, xv.z, xv.w};
        #pragma unroll
        for (int k = 0; k < 4; ++k) {
            int c = c0 + k;
            float mean = sums[c] * inv_n;
            float var = sumsq[c] * inv_n - mean * mean;
            float inv = rsqrtf(var + EPSBN);
            float v = (o[k] - mean) * inv * gamma[c] + beta[c];
            o[k] = xi[k] + fmaxf(v, 0.f);
        }
        ((float4*)y)[i] = make_float4(o[0], o[1], o[2], o[3]);
    }
}

extern "C" void kernel_launch(void* const* d_in, const int* in_sizes, int n_in,
                              void* d_out, int out_size, void* d_ws, size_t ws_size,
                              hipStream_t stream) {
    const float* x     = (const float*)d_in[0];
    const int*   src   = (const int*)d_in[1];
    const int*   dst   = (const int*)d_in[2];
    const float* W     = (const float*)d_in[3];
    const float* bvec  = (const float*)d_in[4];
    const float* gamma = (const float*)d_in[5];
    const float* beta  = (const float*)d_in[6];
    float* out = (float*)d_out;   // used as agg, then y, in place

    const int n_nodes = in_sizes[0] / DFEAT;
    const int E = in_sizes[1];
    const int NB = (n_nodes + SCB - 1) / SCB;
    const int C = (E + CHUNK - 1) >> CHUNK_LG;          // edge chunks
    const int P = (n_nodes + RNG - 1) / RNG;            // node partitions
    const int N_pad = P * RNG;

    // ws: epack (E int2) | lrank (E u16) | cnt (C*N_pad u16) | deg_out N |
    //     sums 64 | sumsq 64 | deg_in N | row_start N+1 | bsum 64
    char* wsb = (char*)d_ws;
    int2* epack          = (int2*)wsb;
    unsigned short* lrank = (unsigned short*)(wsb + (size_t)E * 8);
    unsigned short* cnt   = lrank + E;
    int*  deg_out_i  = (int*)(cnt + (size_t)C * N_pad);
    float* sums      = (float*)(deg_out_i + n_nodes);
    float* sumsq     = sums + DFEAT;
    int*  deg_in_i   = (int*)(sumsq + DFEAT);
    int*  row_start  = deg_in_i + n_nodes;
    int*  bsum       = row_start + n_nodes + 1;

    // zero: deg_out + sums + sumsq (contiguous). deg_in/cnt fully overwritten.
    hipMemsetAsync(deg_out_i, 0, ((size_t)n_nodes + 2 * DFEAT) * sizeof(int), stream);

    hist2d_kernel<<<dim3(C, P), 256, 0, stream>>>(src, dst, lrank, cnt, deg_out_i,
                                                  E, n_nodes, N_pad);

    colscan_kernel<<<(n_nodes + 255) / 256, 256, 0, stream>>>(cnt, deg_in_i,
                                                              n_nodes, N_pad, C);

    scan1_kernel<<<NB, 256, 0, stream>>>(deg_in_i, bsum, n_nodes);
    scan2_kernel<<<1, 64, 0, stream>>>(bsum, row_start, NB, n_nodes);
    scan3_kernel<<<NB, 256, 0, stream>>>(deg_in_i, bsum, row_start, n_nodes);

    fill_kernel<<<(E + 255) / 256, 256, 0, stream>>>(src, dst, lrank, cnt, deg_out_i,
                                                     row_start, epack, E, N_pad);

    spmm_kernel<<<(n_nodes + 3) / 4, 256, 0, stream>>>(x, row_start, epack, out, n_nodes);

    int ntiles = (n_nodes + 63) / 64;
    gemm_bn_kernel<<<ntiles, 256, 0, stream>>>(W, bvec, out, sums, sumsq, n_nodes);

    int n4 = n_nodes * DFEAT / 4;
    bn_relu_res_kernel<<<(n4 + 255) / 256, 256, 0, stream>>>(
        x, sums, sumsq, gamma, beta, out, n4, 1.0f / (float)n_nodes);
}

// Round 9
// 316.996 us; speedup vs baseline: 3.1068x; 1.1454x over previous
//
#include <hip/hip_runtime.h>
#include <hip/hip_bf16.h>

#define DFEAT 64
#define EPSBN 1e-5f
#define SCB 2048      // elements per scan block (256 threads x 8)
#define CHUNK_LG 16
#define CHUNK (1 << CHUNK_LG)   // 65536 edges per chunk
#define RNG 8192      // nodes per partition (one packed 32KB LDS histogram)

// ---------------- LDS-privatized PACKED dual histogram + chunk-local rank ----------------
// one 32KB LDS array: low16 = dst count, high16 = src count (per-chunk-per-node
// counts are tiny; no overflow for this graph). 32KB -> ~5 blocks/CU vs round-8's
// 2 (64KB, 13% occupancy). int4 edge loads + manual prefetch for MLP.
__global__ __launch_bounds__(256) void hist2d_kernel(
        const int* __restrict__ src, const int* __restrict__ dst,
        unsigned short* __restrict__ lrank, unsigned short* __restrict__ cnt,
        int* __restrict__ deg_out, int E, int N, int N_pad) {
    __shared__ int h[RNG];
    int tid = threadIdx.x;
    int c = blockIdx.x, p = blockIdx.y;
    int nbeg = p * RNG;
    for (int i = tid; i < RNG; i += 256) h[i] = 0;
    __syncthreads();

    int ebeg = c << CHUNK_LG;
    int eend = min(ebeg + CHUNK, E);
    int nvec = (eend - ebeg) >> 2;              // full int4 groups
    const int4* src4 = (const int4*)(src + ebeg);
    const int4* dst4 = (const int4*)(dst + ebeg);

    int i = tid;
    int4 s4 = make_int4(0, 0, 0, 0), d4 = s4;
    if (i < nvec) { s4 = src4[i]; d4 = dst4[i]; }
    while (i < nvec) {
        int inext = i + 256;
        int4 sn = make_int4(0, 0, 0, 0), dn = sn;
        if (inext < nvec) { sn = src4[inext]; dn = dst4[inext]; }   // prefetch
        int e = ebeg + (i << 2);
        {
            unsigned int so, dof;
            so = (unsigned int)(s4.x - nbeg); if (so < RNG) atomicAdd(&h[so], 0x10000);
            so = (unsigned int)(s4.y - nbeg); if (so < RNG) atomicAdd(&h[so], 0x10000);
            so = (unsigned int)(s4.z - nbeg); if (so < RNG) atomicAdd(&h[so], 0x10000);
            so = (unsigned int)(s4.w - nbeg); if (so < RNG) atomicAdd(&h[so], 0x10000);
            dof = (unsigned int)(d4.x - nbeg);
            if (dof < RNG) lrank[e + 0] = (unsigned short)(atomicAdd(&h[dof], 1) & 0xffff);
            dof = (unsigned int)(d4.y - nbeg);
            if (dof < RNG) lrank[e + 1] = (unsigned short)(atomicAdd(&h[dof], 1) & 0xffff);
            dof = (unsigned int)(d4.z - nbeg);
            if (dof < RNG) lrank[e + 2] = (unsigned short)(atomicAdd(&h[dof], 1) & 0xffff);
            dof = (unsigned int)(d4.w - nbeg);
            if (dof < RNG) lrank[e + 3] = (unsigned short)(atomicAdd(&h[dof], 1) & 0xffff);
        }
        s4 = sn; d4 = dn; i = inext;
    }
    // tail edges (last partial int4 group)
    for (int e = ebeg + (nvec << 2) + tid; e < eend; e += 256) {
        unsigned int so = (unsigned int)(src[e] - nbeg);
        unsigned int dof = (unsigned int)(dst[e] - nbeg);
        if (so < RNG) atomicAdd(&h[so], 0x10000);
        if (dof < RNG) lrank[e] = (unsigned short)(atomicAdd(&h[dof], 1) & 0xffff);
    }
    __syncthreads();

    for (int i2 = tid; i2 < RNG; i2 += 256) {
        int n = nbeg + i2;
        if (n < N) {
            unsigned int v = (unsigned int)h[i2];
            unsigned int vo = v >> 16;
            if (vo) atomicAdd(&deg_out[n], (int)vo);   // contiguous lanes -> batched
            cnt[(size_t)c * N_pad + n] = (unsigned short)(v & 0xffffu);
        }
    }
}

// ---------------- column scan: per-node exclusive prefix over chunks ----------------
__global__ void colscan_kernel(unsigned short* __restrict__ cnt,
                               int* __restrict__ deg_in, int N, int N_pad, int C) {
    int n = blockIdx.x * blockDim.x + threadIdx.x;
    if (n >= N) return;
    int run = 0;
    for (int c = 0; c < C; ++c) {
        size_t idx = (size_t)c * N_pad + n;
        int v = cnt[idx];
        cnt[idx] = (unsigned short)run;
        run += v;
    }
    deg_in[n] = run;
}

// ---------------- scan pass 1: per-block sums of deg_in ----------------
__global__ void scan1_kernel(const int* __restrict__ deg, int* __restrict__ bsum, int N) {
    __shared__ int red[256];
    int t = threadIdx.x;
    int base = blockIdx.x * SCB + t * 8;
    int s = 0;
    #pragma unroll
    for (int j = 0; j < 8; ++j) { int idx = base + j; if (idx < N) s += deg[idx]; }
    red[t] = s;
    __syncthreads();
    for (int d = 128; d > 0; d >>= 1) { if (t < d) red[t] += red[t + d]; __syncthreads(); }
    if (t == 0) bsum[blockIdx.x] = red[0];
}

// ---------------- scan pass 2: one-wave shuffle exclusive scan (NB <= 64) ----------------
__global__ void scan2_kernel(int* __restrict__ bsum, int* __restrict__ row_start, int NB, int N) {
    int lane = threadIdx.x & 63;
    int v = (lane < NB) ? bsum[lane] : 0;
    int incl = v;
    #pragma unroll
    for (int off = 1; off < 64; off <<= 1) {
        int t = __shfl_up(incl, off);
        if (lane >= off) incl += t;
    }
    if (lane < NB) bsum[lane] = incl - v;
    if (lane == 63) row_start[N] = incl;   // total == E
}

// ---------------- scan pass 3: full exclusive scan -> row_start ----------------
__global__ void scan3_kernel(const int* __restrict__ deg, const int* __restrict__ bsum,
                             int* __restrict__ row_start, int N) {
    __shared__ int sc[256];
    int t = threadIdx.x;
    int base = blockIdx.x * SCB + t * 8;
    int v[8], ex[8];
    int s = 0;
    #pragma unroll
    for (int j = 0; j < 8; ++j) {
        int idx = base + j;
        v[j] = (idx < N) ? deg[idx] : 0;
        ex[j] = s;
        s += v[j];
    }
    sc[t] = s;
    __syncthreads();
    for (int d = 1; d < 256; d <<= 1) {
        int vv = (t >= d) ? sc[t - d] : 0;
        __syncthreads();
        sc[t] += vv;
        __syncthreads();
    }
    int toff = sc[t] - s + bsum[blockIdx.x];
    #pragma unroll
    for (int j = 0; j < 8; ++j) {
        int idx = base + j;
        if (idx < N) row_start[idx] = toff + ex[j];
    }
}

// ---------------- place edges: slot = row_start[d] + pref[c][d] + lrank[e] ----------------
__global__ void fill_kernel(const int* __restrict__ src, const int* __restrict__ dst,
                            const unsigned short* __restrict__ lrank,
                            const unsigned short* __restrict__ cnt,
                            const int* __restrict__ deg_out, const int* __restrict__ row_start,
                            int2* __restrict__ epack, int E, int N_pad) {
    int e = blockIdx.x * blockDim.x + threadIdx.x;
    if (e < E) {
        int d = dst[e], s = src[e];
        int c = e >> CHUNK_LG;
        float coef = rsqrtf((float)max(deg_out[s], 1));
        int slot = row_start[d] + (int)cnt[(size_t)c * N_pad + d] + (int)lrank[e];
        epack[slot] = make_int2(s, __float_as_int(coef));
    }
}

// ---------------- SpMM: ONE dst row per wave, massive TLP, no atomics ----------------
__global__ __launch_bounds__(256, 6) void spmm_kernel(
        const float* __restrict__ x, const int* __restrict__ row_start,
        const int2* __restrict__ epack, float* __restrict__ agg, int N) {
    int lane = threadIdx.x & 63;
    int r = blockIdx.x * 4 + (threadIdx.x >> 6);
    if (r >= N) return;
    int beg = row_start[r];
    int end = row_start[r + 1];
    float acc = 0.f;
    for (int cb = beg; cb < end; cb += 64) {
        int take = min(64, end - cb);
        int2 p = (lane < take) ? epack[cb + lane] : make_int2(0, 0);
        int j = 0;
        for (; j + 8 <= take; j += 8) {
            int sj[8]; float cj[8], v[8];
            #pragma unroll
            for (int u = 0; u < 8; ++u) {
                sj[u] = __shfl(p.x, j + u);
                cj[u] = __int_as_float(__shfl(p.y, j + u));
            }
            #pragma unroll
            for (int u = 0; u < 8; ++u) v[u] = x[(size_t)sj[u] * DFEAT + lane];
            #pragma unroll
            for (int u = 0; u < 8; ++u) acc = fmaf(v[u], cj[u], acc);
        }
        for (; j < take; ++j) {
            int s = __shfl(p.x, j);
            float c = __int_as_float(__shfl(p.y, j));
            acc = fmaf(x[(size_t)s * DFEAT + lane], c, acc);
        }
    }
    acc *= rsqrtf((float)max(end - beg, 1));   // norm_dst
    agg[(size_t)r * DFEAT + lane] = acc;       // exclusive row: plain coalesced store
}

// ---------------- GEMM (in place on y==agg) + BN stats ----------------
__global__ __launch_bounds__(256) void gemm_bn_kernel(
        const float* __restrict__ W, const float* __restrict__ bvec,
        float* __restrict__ y, float* __restrict__ sums, float* __restrict__ sumsq,
        int N) {
    __shared__ float Wlds[DFEAT * DFEAT];
    __shared__ float A[64][65];
    __shared__ float red_s[4][DFEAT];
    __shared__ float red_q[4][DFEAT];
    int tid = threadIdx.x;
    int r0 = blockIdx.x * 64;

    for (int i = tid; i < DFEAT * DFEAT; i += 256) Wlds[i] = W[i];

    const float4* y4 = (const float4*)y;
    #pragma unroll
    for (int k = 0; k < 4; ++k) {
        int f = tid + k * 256;            // float4 slot in tile: 0..1023
        int row = f >> 4;                 // 16 float4 per row
        int c4 = (f & 15) << 2;
        float4 val = make_float4(0.f, 0.f, 0.f, 0.f);
        if (r0 + row < N) val = y4[(size_t)(r0 + row) * 16 + (f & 15)];
        A[row][c4 + 0] = val.x; A[row][c4 + 1] = val.y;
        A[row][c4 + 2] = val.z; A[row][c4 + 3] = val.w;
    }
    __syncthreads();

    int w = tid >> 6;
    int wu = __builtin_amdgcn_readfirstlane(w);
    int lane = tid & 63;
    int c0 = wu * 16;
    float acc[16];
    #pragma unroll
    for (int cc = 0; cc < 16; ++cc) acc[cc] = bvec[c0 + cc];

    #pragma unroll 8
    for (int k = 0; k < 64; ++k) {
        float a = A[lane][k];                    // (lane+k)%32 -> 2-way, free
        const float* wr = &Wlds[k * DFEAT + c0]; // wave-uniform LDS broadcast
        #pragma unroll
        for (int cc = 0; cc < 16; ++cc) acc[cc] = fmaf(a, wr[cc], acc[cc]);
    }

    int r = r0 + lane;
    if (r < N) {
        float4* yp = (float4*)&y[(size_t)r * DFEAT + c0];
        yp[0] = make_float4(acc[0],  acc[1],  acc[2],  acc[3]);
        yp[1] = make_float4(acc[4],  acc[5],  acc[6],  acc[7]);
        yp[2] = make_float4(acc[8],  acc[9],  acc[10], acc[11]);
        yp[3] = make_float4(acc[12], acc[13], acc[14], acc[15]);
    } else {
        #pragma unroll
        for (int cc = 0; cc < 16; ++cc) acc[cc] = 0.f;   // pad rows: 0 into BN stats
    }

    #pragma unroll
    for (int cc = 0; cc < 16; ++cc) {
        float v1 = acc[cc];
        float v2 = acc[cc] * acc[cc];
        for (int off = 32; off > 0; off >>= 1) {
            v1 += __shfl_down(v1, off);
            v2 += __shfl_down(v2, off);
        }
        if (lane == 0) {
            red_s[w][c0 + cc] = v1;   // col c is owned by wave c>>4 only
            red_q[w][c0 + cc] = v2;
        }
    }
    __syncthreads();
    if (w == 0) {
        // one wave-wide atomic instruction: 64 lanes -> 64 consecutive floats
        atomicAdd(&sums[lane],  red_s[lane >> 4][lane]);
        atomicAdd(&sumsq[lane], red_q[lane >> 4][lane]);
    }
}

// ---------------- BN (batch stats) + ReLU + residual, float4, in place on y ----------------
__global__ void bn_relu_res_kernel(const float* __restrict__ x,
                                   const float* __restrict__ sums,
                                   const float* __restrict__ sumsq,
                                   const float* __restrict__ gamma,
                                   const float* __restrict__ beta,
                                   float* __restrict__ y, int n4, float inv_n) {
    int i = blockIdx.x * blockDim.x + threadIdx.x;   // float4 index
    if (i < n4) {
        int c0 = (i << 2) & (DFEAT - 1);
        float4 yv = ((const float4*)y)[i];
        float4 xv = ((const float4*)x)[i];
        float o[4] = {yv.x, yv.y, yv.z, yv.w};
        float xi[4] = {xv.x, xv.y, xv.z, xv.w};
        #pragma unroll
        for (int k = 0; k < 4; ++k) {
            int c = c0 + k;
            float mean = sums[c] * inv_n;
            float var = sumsq[c] * inv_n - mean * mean;
            float inv = rsqrtf(var + EPSBN);
            float v = (o[k] - mean) * inv * gamma[c] + beta[c];
            o[k] = xi[k] + fmaxf(v, 0.f);
        }
        ((float4*)y)[i] = make_float4(o[0], o[1], o[2], o[3]);
    }
}

extern "C" void kernel_launch(void* const* d_in, const int* in_sizes, int n_in,
                              void* d_out, int out_size, void* d_ws, size_t ws_size,
                              hipStream_t stream) {
    const float* x     = (const float*)d_in[0];
    const int*   src   = (const int*)d_in[1];
    const int*   dst   = (const int*)d_in[2];
    const float* W     = (const float*)d_in[3];
    const float* bvec  = (const float*)d_in[4];
    const float* gamma = (const float*)d_in[5];
    const float* beta  = (const float*)d_in[6];
    float* out = (float*)d_out;   // used as agg, then y, in place

    const int n_nodes = in_sizes[0] / DFEAT;
    const int E = in_sizes[1];
    const int NB = (n_nodes + SCB - 1) / SCB;
    const int C = (E + CHUNK - 1) >> CHUNK_LG;          // edge chunks
    const int P = (n_nodes + RNG - 1) / RNG;            // node partitions
    const int N_pad = P * RNG;

    // ws: epack (E int2) | lrank (E u16) | cnt (C*N_pad u16) | deg_out N |
    //     sums 64 | sumsq 64 | deg_in N | row_start N+1 | bsum 64
    char* wsb = (char*)d_ws;
    int2* epack          = (int2*)wsb;
    unsigned short* lrank = (unsigned short*)(wsb + (size_t)E * 8);
    unsigned short* cnt   = lrank + E;
    int*  deg_out_i  = (int*)(cnt + (size_t)C * N_pad);
    float* sums      = (float*)(deg_out_i + n_nodes);
    float* sumsq     = sums + DFEAT;
    int*  deg_in_i   = (int*)(sumsq + DFEAT);
    int*  row_start  = deg_in_i + n_nodes;
    int*  bsum       = row_start + n_nodes + 1;

    // zero: deg_out + sums + sumsq (contiguous). deg_in/cnt fully overwritten.
    hipMemsetAsync(deg_out_i, 0, ((size_t)n_nodes + 2 * DFEAT) * sizeof(int), stream);

    hist2d_kernel<<<dim3(C, P), 256, 0, stream>>>(src, dst, lrank, cnt, deg_out_i,
                                                  E, n_nodes, N_pad);

    colscan_kernel<<<(n_nodes + 255) / 256, 256, 0, stream>>>(cnt, deg_in_i,
                                                              n_nodes, N_pad, C);

    scan1_kernel<<<NB, 256, 0, stream>>>(deg_in_i, bsum, n_nodes);
    scan2_kernel<<<1, 64, 0, stream>>>(bsum, row_start, NB, n_nodes);
    scan3_kernel<<<NB, 256, 0, stream>>>(deg_in_i, bsum, row_start, n_nodes);

    fill_kernel<<<(E + 255) / 256, 256, 0, stream>>>(src, dst, lrank, cnt, deg_out_i,
                                                     row_start, epack, E, N_pad);

    spmm_kernel<<<(n_nodes + 3) / 4, 256, 0, stream>>>(x, row_start, epack, out, n_nodes);

    int ntiles = (n_nodes + 63) / 64;
    gemm_bn_kernel<<<ntiles, 256, 0, stream>>>(W, bvec, out, sums, sumsq, n_nodes);

    int n4 = n_nodes * DFEAT / 4;
    bn_relu_res_kernel<<<(n4 + 255) / 256, 256, 0, stream>>>(
        x, sums, sumsq, gamma, beta, out, n4, 1.0f / (float)n_nodes);
}

// Round 10
// 316.223 us; speedup vs baseline: 3.1144x; 1.0024x over previous
//
#include <hip/hip_runtime.h>
#include <hip/hip_bf16.h>

#define DFEAT 64
#define EPSBN 1e-5f
#define SCB 2048      // elements per scan block (256 threads x 8)
#define CHUNK_LG 15
#define CHUNK (1 << CHUNK_LG)   // 32768 edges per chunk (637 blocks -> 2.5/CU)
#define RNG 8192      // nodes per partition (one packed 32KB LDS histogram)

// ---------------- LDS-privatized PACKED dual histogram + chunk-local rank ----------------
// one 32KB LDS array: low16 = dst count, high16 = src count. int4 edge loads +
// manual prefetch. CHUNK halved vs round-8: grid 325 -> 637 blocks (was the
// occupancy limiter: 1.3 blocks/CU vs the 5 the 32KB LDS allows).
__global__ __launch_bounds__(256) void hist2d_kernel(
        const int* __restrict__ src, const int* __restrict__ dst,
        unsigned short* __restrict__ lrank, unsigned short* __restrict__ cnt,
        int* __restrict__ deg_out, int E, int N, int N_pad) {
    __shared__ int h[RNG];
    int tid = threadIdx.x;
    int c = blockIdx.x, p = blockIdx.y;
    int nbeg = p * RNG;
    for (int i = tid; i < RNG; i += 256) h[i] = 0;
    __syncthreads();

    int ebeg = c << CHUNK_LG;
    int eend = min(ebeg + CHUNK, E);
    int nvec = (eend - ebeg) >> 2;              // full int4 groups
    const int4* src4 = (const int4*)(src + ebeg);
    const int4* dst4 = (const int4*)(dst + ebeg);

    int i = tid;
    int4 s4 = make_int4(0, 0, 0, 0), d4 = s4;
    if (i < nvec) { s4 = src4[i]; d4 = dst4[i]; }
    while (i < nvec) {
        int inext = i + 256;
        int4 sn = make_int4(0, 0, 0, 0), dn = sn;
        if (inext < nvec) { sn = src4[inext]; dn = dst4[inext]; }   // prefetch
        int e = ebeg + (i << 2);
        {
            unsigned int so, dof;
            so = (unsigned int)(s4.x - nbeg); if (so < RNG) atomicAdd(&h[so], 0x10000);
            so = (unsigned int)(s4.y - nbeg); if (so < RNG) atomicAdd(&h[so], 0x10000);
            so = (unsigned int)(s4.z - nbeg); if (so < RNG) atomicAdd(&h[so], 0x10000);
            so = (unsigned int)(s4.w - nbeg); if (so < RNG) atomicAdd(&h[so], 0x10000);
            dof = (unsigned int)(d4.x - nbeg);
            if (dof < RNG) lrank[e + 0] = (unsigned short)(atomicAdd(&h[dof], 1) & 0xffff);
            dof = (unsigned int)(d4.y - nbeg);
            if (dof < RNG) lrank[e + 1] = (unsigned short)(atomicAdd(&h[dof], 1) & 0xffff);
            dof = (unsigned int)(d4.z - nbeg);
            if (dof < RNG) lrank[e + 2] = (unsigned short)(atomicAdd(&h[dof], 1) & 0xffff);
            dof = (unsigned int)(d4.w - nbeg);
            if (dof < RNG) lrank[e + 3] = (unsigned short)(atomicAdd(&h[dof], 1) & 0xffff);
        }
        s4 = sn; d4 = dn; i = inext;
    }
    for (int e = ebeg + (nvec << 2) + tid; e < eend; e += 256) {
        unsigned int so = (unsigned int)(src[e] - nbeg);
        unsigned int dof = (unsigned int)(dst[e] - nbeg);
        if (so < RNG) atomicAdd(&h[so], 0x10000);
        if (dof < RNG) lrank[e] = (unsigned short)(atomicAdd(&h[dof], 1) & 0xffff);
    }
    __syncthreads();

    for (int i2 = tid; i2 < RNG; i2 += 256) {
        int n = nbeg + i2;
        if (n < N) {
            unsigned int v = (unsigned int)h[i2];
            unsigned int vo = v >> 16;
            if (vo) atomicAdd(&deg_out[n], (int)vo);   // contiguous lanes -> batched
            cnt[(size_t)c * N_pad + n] = (unsigned short)(v & 0xffffu);
        }
    }
}

// ---------------- column scan: per-node exclusive prefix over chunks ----------------
__global__ void colscan_kernel(unsigned short* __restrict__ cnt,
                               int* __restrict__ deg_in, int N, int N_pad, int C) {
    int n = blockIdx.x * blockDim.x + threadIdx.x;
    if (n >= N) return;
    int run = 0;
    for (int c = 0; c < C; ++c) {
        size_t idx = (size_t)c * N_pad + n;
        int v = cnt[idx];
        cnt[idx] = (unsigned short)run;
        run += v;
    }
    deg_in[n] = run;
}

// ---------------- scan pass 1: per-block sums of deg_in ----------------
__global__ void scan1_kernel(const int* __restrict__ deg, int* __restrict__ bsum, int N) {
    __shared__ int red[256];
    int t = threadIdx.x;
    int base = blockIdx.x * SCB + t * 8;
    int s = 0;
    #pragma unroll
    for (int j = 0; j < 8; ++j) { int idx = base + j; if (idx < N) s += deg[idx]; }
    red[t] = s;
    __syncthreads();
    for (int d = 128; d > 0; d >>= 1) { if (t < d) red[t] += red[t + d]; __syncthreads(); }
    if (t == 0) bsum[blockIdx.x] = red[0];
}

// ---------------- scan pass 2: one-wave shuffle exclusive scan (NB <= 64) ----------------
__global__ void scan2_kernel(int* __restrict__ bsum, int* __restrict__ row_start, int NB, int N) {
    int lane = threadIdx.x & 63;
    int v = (lane < NB) ? bsum[lane] : 0;
    int incl = v;
    #pragma unroll
    for (int off = 1; off < 64; off <<= 1) {
        int t = __shfl_up(incl, off);
        if (lane >= off) incl += t;
    }
    if (lane < NB) bsum[lane] = incl - v;
    if (lane == 63) row_start[N] = incl;   // total == E
}

// ---------------- scan pass 3: full exclusive scan -> row_start ----------------
__global__ void scan3_kernel(const int* __restrict__ deg, const int* __restrict__ bsum,
                             int* __restrict__ row_start, int N) {
    __shared__ int sc[256];
    int t = threadIdx.x;
    int base = blockIdx.x * SCB + t * 8;
    int v[8], ex[8];
    int s = 0;
    #pragma unroll
    for (int j = 0; j < 8; ++j) {
        int idx = base + j;
        v[j] = (idx < N) ? deg[idx] : 0;
        ex[j] = s;
        s += v[j];
    }
    sc[t] = s;
    __syncthreads();
    for (int d = 1; d < 256; d <<= 1) {
        int vv = (t >= d) ? sc[t - d] : 0;
        __syncthreads();
        sc[t] += vv;
        __syncthreads();
    }
    int toff = sc[t] - s + bsum[blockIdx.x];
    #pragma unroll
    for (int j = 0; j < 8; ++j) {
        int idx = base + j;
        if (idx < N) row_start[idx] = toff + ex[j];
    }
}

// ---------------- place edges: slot = row_start[d] + pref[c][d] + lrank[e] ----------------
__global__ void fill_kernel(const int* __restrict__ src, const int* __restrict__ dst,
                            const unsigned short* __restrict__ lrank,
                            const unsigned short* __restrict__ cnt,
                            const int* __restrict__ deg_out, const int* __restrict__ row_start,
                            int2* __restrict__ epack, int E, int N_pad) {
    int e = blockIdx.x * blockDim.x + threadIdx.x;
    if (e < E) {
        int d = dst[e], s = src[e];
        int c = e >> CHUNK_LG;
        float coef = rsqrtf((float)max(deg_out[s], 1));
        int slot = row_start[d] + (int)cnt[(size_t)c * N_pad + d] + (int)lrank[e];
        epack[slot] = make_int2(s, __float_as_int(coef));
    }
}

// ---------------- SpMM: ONE dst row per wave, massive TLP, no atomics ----------------
__global__ __launch_bounds__(256, 6) void spmm_kernel(
        const float* __restrict__ x, const int* __restrict__ row_start,
        const int2* __restrict__ epack, float* __restrict__ agg, int N) {
    int lane = threadIdx.x & 63;
    int r = blockIdx.x * 4 + (threadIdx.x >> 6);
    if (r >= N) return;
    int beg = row_start[r];
    int end = row_start[r + 1];
    float acc = 0.f;
    for (int cb = beg; cb < end; cb += 64) {
        int take = min(64, end - cb);
        int2 p = (lane < take) ? epack[cb + lane] : make_int2(0, 0);
        int j = 0;
        for (; j + 8 <= take; j += 8) {
            int sj[8]; float cj[8], v[8];
            #pragma unroll
            for (int u = 0; u < 8; ++u) {
                sj[u] = __shfl(p.x, j + u);
                cj[u] = __int_as_float(__shfl(p.y, j + u));
            }
            #pragma unroll
            for (int u = 0; u < 8; ++u) v[u] = x[(size_t)sj[u] * DFEAT + lane];
            #pragma unroll
            for (int u = 0; u < 8; ++u) acc = fmaf(v[u], cj[u], acc);
        }
        for (; j < take; ++j) {
            int s = __shfl(p.x, j);
            float c = __int_as_float(__shfl(p.y, j));
            acc = fmaf(x[(size_t)s * DFEAT + lane], c, acc);
        }
    }
    acc *= rsqrtf((float)max(end - beg, 1));   // norm_dst
    agg[(size_t)r * DFEAT + lane] = acc;       // exclusive row: plain coalesced store
}

// ---------------- GEMM (in place on y==agg) + BN stats ----------------
// W is read via wave-uniform addresses -> s_load into SGPRs (free FMA operand);
// no Wlds copy. LDS 35KB -> 17KB, 8 blocks/CU.
__global__ __launch_bounds__(256, 8) void gemm_bn_kernel(
        const float* __restrict__ W, const float* __restrict__ bvec,
        float* __restrict__ y, float* __restrict__ sums, float* __restrict__ sumsq,
        int N) {
    __shared__ float A[64][65];
    __shared__ float red_s[DFEAT];
    __shared__ float red_q[DFEAT];
    int tid = threadIdx.x;
    int r0 = blockIdx.x * 64;

    const float4* y4 = (const float4*)y;
    #pragma unroll
    for (int k = 0; k < 4; ++k) {
        int f = tid + k * 256;            // float4 slot in tile: 0..1023
        int row = f >> 4;                 // 16 float4 per row
        int c4 = (f & 15) << 2;
        float4 val = make_float4(0.f, 0.f, 0.f, 0.f);
        if (r0 + row < N) val = y4[(size_t)(r0 + row) * 16 + (f & 15)];
        A[row][c4 + 0] = val.x; A[row][c4 + 1] = val.y;
        A[row][c4 + 2] = val.z; A[row][c4 + 3] = val.w;
    }
    __syncthreads();

    int w = tid >> 6;
    int wu = __builtin_amdgcn_readfirstlane(w);
    int lane = tid & 63;
    int c0 = wu * 16;
    float acc[16];
    #pragma unroll
    for (int cc = 0; cc < 16; ++cc) acc[cc] = bvec[c0 + cc];   // uniform -> s_load

    #pragma unroll 4
    for (int k = 0; k < 64; ++k) {
        float a = A[lane][k];                    // (lane+k)%32 -> 2-way, free
        const float* wr = &W[k * DFEAT + c0];    // uniform -> s_load_dwordx16
        #pragma unroll
        for (int cc = 0; cc < 16; ++cc) acc[cc] = fmaf(a, wr[cc], acc[cc]);
    }

    int r = r0 + lane;
    if (r < N) {
        float4* yp = (float4*)&y[(size_t)r * DFEAT + c0];
        yp[0] = make_float4(acc[0],  acc[1],  acc[2],  acc[3]);
        yp[1] = make_float4(acc[4],  acc[5],  acc[6],  acc[7]);
        yp[2] = make_float4(acc[8],  acc[9],  acc[10], acc[11]);
        yp[3] = make_float4(acc[12], acc[13], acc[14], acc[15]);
    } else {
        #pragma unroll
        for (int cc = 0; cc < 16; ++cc) acc[cc] = 0.f;   // pad rows: 0 into BN stats
    }

    #pragma unroll
    for (int cc = 0; cc < 16; ++cc) {
        float v1 = acc[cc];
        float v2 = acc[cc] * acc[cc];
        for (int off = 32; off > 0; off >>= 1) {
            v1 += __shfl_down(v1, off);
            v2 += __shfl_down(v2, off);
        }
        if (lane == 0) {
            red_s[c0 + cc] = v1;   // col c is owned by wave c>>4 only
            red_q[c0 + cc] = v2;
        }
    }
    __syncthreads();
    if (w == 0) {
        // one wave-wide atomic instruction: 64 lanes -> 64 consecutive floats
        atomicAdd(&sums[lane],  red_s[lane]);
        atomicAdd(&sumsq[lane], red_q[lane]);
    }
}

// ---------------- BN (batch stats) + ReLU + residual, float4, in place on y ----------------
__global__ void bn_relu_res_kernel(const float* __restrict__ x,
                                   const float* __restrict__ sums,
                                   const float* __restrict__ sumsq,
                                   const float* __restrict__ gamma,
                                   const float* __restrict__ beta,
                                   float* __restrict__ y, int n4, float inv_n) {
    int i = blockIdx.x * blockDim.x + threadIdx.x;   // float4 index
    if (i < n4) {
        int c0 = (i << 2) & (DFEAT - 1);
        float4 yv = ((const float4*)y)[i];
        float4 xv = ((const float4*)x)[i];
        float o[4] = {yv.x, yv.y, yv.z, yv.w};
        float xi[4] = {xv.x, xv.y, xv.z, xv.w};
        #pragma unroll
        for (int k = 0; k < 4; ++k) {
            int c = c0 + k;
            float mean = sums[c] * inv_n;
            float var = sumsq[c] * inv_n - mean * mean;
            float inv = rsqrtf(var + EPSBN);
            float v = (o[k] - mean) * inv * gamma[c] + beta[c];
            o[k] = xi[k] + fmaxf(v, 0.f);
        }
        ((float4*)y)[i] = make_float4(o[0], o[1], o[2], o[3]);
    }
}

extern "C" void kernel_launch(void* const* d_in, const int* in_sizes, int n_in,
                              void* d_out, int out_size, void* d_ws, size_t ws_size,
                              hipStream_t stream) {
    const float* x     = (const float*)d_in[0];
    const int*   src   = (const int*)d_in[1];
    const int*   dst   = (const int*)d_in[2];
    const float* W     = (const float*)d_in[3];
    const float* bvec  = (const float*)d_in[4];
    const float* gamma = (const float*)d_in[5];
    const float* beta  = (const float*)d_in[6];
    float* out = (float*)d_out;   // used as agg, then y, in place

    const int n_nodes = in_sizes[0] / DFEAT;
    const int E = in_sizes[1];
    const int NB = (n_nodes + SCB - 1) / SCB;
    const int C = (E + CHUNK - 1) >> CHUNK_LG;          // edge chunks
    const int P = (n_nodes + RNG - 1) / RNG;            // node partitions
    const int N_pad = P * RNG;

    // ws: epack (E int2) | lrank (E u16) | cnt (C*N_pad u16) | deg_out N |
    //     sums 64 | sumsq 64 | deg_in N | row_start N+1 | bsum 64
    char* wsb = (char*)d_ws;
    int2* epack          = (int2*)wsb;
    unsigned short* lrank = (unsigned short*)(wsb + (size_t)E * 8);
    unsigned short* cnt   = lrank + E;
    int*  deg_out_i  = (int*)(cnt + (size_t)C * N_pad);
    float* sums      = (float*)(deg_out_i + n_nodes);
    float* sumsq     = sums + DFEAT;
    int*  deg_in_i   = (int*)(sumsq + DFEAT);
    int*  row_start  = deg_in_i + n_nodes;
    int*  bsum       = row_start + n_nodes + 1;

    // zero: deg_out + sums + sumsq (contiguous). deg_in/cnt fully overwritten.
    hipMemsetAsync(deg_out_i, 0, ((size_t)n_nodes + 2 * DFEAT) * sizeof(int), stream);

    hist2d_kernel<<<dim3(C, P), 256, 0, stream>>>(src, dst, lrank, cnt, deg_out_i,
                                                  E, n_nodes, N_pad);

    colscan_kernel<<<(n_nodes + 255) / 256, 256, 0, stream>>>(cnt, deg_in_i,
                                                              n_nodes, N_pad, C);

    scan1_kernel<<<NB, 256, 0, stream>>>(deg_in_i, bsum, n_nodes);
    scan2_kernel<<<1, 64, 0, stream>>>(bsum, row_start, NB, n_nodes);
    scan3_kernel<<<NB, 256, 0, stream>>>(deg_in_i, bsum, row_start, n_nodes);

    fill_kernel<<<(E + 255) / 256, 256, 0, stream>>>(src, dst, lrank, cnt, deg_out_i,
                                                     row_start, epack, E, N_pad);

    spmm_kernel<<<(n_nodes + 3) / 4, 256, 0, stream>>>(x, row_start, epack, out, n_nodes);

    int ntiles = (n_nodes + 63) / 64;
    gemm_bn_kernel<<<ntiles, 256, 0, stream>>>(W, bvec, out, sums, sumsq, n_nodes);

    int n4 = n_nodes * DFEAT / 4;
    bn_relu_res_kernel<<<(n4 + 255) / 256, 256, 0, stream>>>(
        x, sums, sumsq, gamma, beta, out, n4, 1.0f / (float)n_nodes);
}